// Round 6
// baseline (78.752 us; speedup 1.0000x reference)
//
#include <hip/hip_runtime.h>
#include <math.h>

// B=8, N=2048, coords [B,N,3] f32. LDDT loss, upper-triangle formulation:
// both distance matrices are symmetric so num/den over {j>i} equals the
// full-matrix ratio; j>i excludes the diagonal, making the reference's
// true_d > 1e-8 test vacuous for this data.
//
// R6 = R3 skeleton (256-thr blocks, 144 triangle tiles/batch, LDS j-tile,
// broadcast reads) + packed-pair inner loop: two j-points per iteration with
// float2 component math so the backend can emit v_pk_{add,mul,fma}_f32
// (CDNA packed dual-fp32). LDS layout is pair-packed, 64 B per 2-j group:
// 3x ds_read_b128 per 2 j's (was 4), broadcast, conflict-free.
constexpr int B  = 8;
constexpr int N  = 2048;
constexpr int TI = 256;        // i-points per block == threads (4 waves)
constexpr int TJ = 64;         // j-points per tile
constexpr int NG = TJ / 2;     // 32 packed j-pair groups
constexpr int TILES = 144;     // per batch: c in [4a, 32), a in [0,8)
constexpr int WPB = TI / 64;   // waves per block
constexpr int SLOTS = TILES * WPB;   // 576 per batch

__device__ __forceinline__ unsigned long long prefix_mask(int kw)
{
    // lanes l with l < kw
    return (kw >= 64) ? ~0ull : ((kw <= 0) ? 0ull : ((1ull << kw) - 1ull));
}

template <bool CHECK>
__device__ __forceinline__ void inner_loop(
    const float* __restrict__ sj,    // [NG][16]: px01 py01 pz01 tx01 ty01 tz01 pad4
    float pix, float piy, float piz,
    float tix, float tiy, float tiz,
    int k0,                          // j0 - (i0 + 64*wave), CHECK tiles only
    unsigned& c0, unsigned& c1, unsigned& c2, unsigned& c3, unsigned& cd)
{
    #pragma unroll 4
    for (int g = 0; g < NG; ++g) {
        const float4 A = *(const float4*)&sj[g * 16 + 0];   // px0 px1 py0 py1
        const float4 Bv = *(const float4*)&sj[g * 16 + 4];  // pz0 pz1 tx0 tx1
        const float4 C = *(const float4*)&sj[g * 16 + 8];   // ty0 ty1 tz0 tz1

        // packed (2-wide) distance math — component code -> v_pk_* on CDNA
        float dx0 = pix - A.x,  dx1 = pix - A.y;
        float dy0 = piy - A.z,  dy1 = piy - A.w;
        float dz0 = piz - Bv.x, dz1 = piz - Bv.y;
        float pd20 = fmaf(dx0, dx0, fmaf(dy0, dy0, dz0 * dz0));
        float pd21 = fmaf(dx1, dx1, fmaf(dy1, dy1, dz1 * dz1));

        float ex0 = tix - Bv.z, ex1 = tix - Bv.w;
        float ey0 = tiy - C.x,  ey1 = tiy - C.y;
        float ez0 = tiz - C.z,  ez1 = tiz - C.w;
        float td20 = fmaf(ex0, ex0, fmaf(ey0, ey0, ez0 * ez0));
        float td21 = fmaf(ex1, ex1, fmaf(ey1, ey1, ez1 * ez1));

        // local mask (squared domain): true_d < 15; j>i excludes diagonal
        unsigned long long m0 = __ballot(td20 < 225.0f);
        unsigned long long m1 = __ballot(td21 < 225.0f);
        if (CHECK) {
            // lane l allowed iff l < k0 + j  (j = 2g, 2g+1) — SALU masks
            m0 &= prefix_mask(k0 + 2 * g);
            m1 &= prefix_mask(k0 + 2 * g + 1);
        }

        float diff0 = fabsf(__builtin_amdgcn_sqrtf(pd20) - __builtin_amdgcn_sqrtf(td20));
        float diff1 = fabsf(__builtin_amdgcn_sqrtf(pd21) - __builtin_amdgcn_sqrtf(td21));

        // cumulative bins: score = .5*[d<.5]+.25*[d<1]+.125*[d<2]+.125*[d<4]
        c0 += __popcll(m0 & __ballot(diff0 < 0.5f));
        c1 += __popcll(m0 & __ballot(diff0 < 1.0f));
        c2 += __popcll(m0 & __ballot(diff0 < 2.0f));
        c3 += __popcll(m0 & __ballot(diff0 < 4.0f));
        cd += __popcll(m0);
        c0 += __popcll(m1 & __ballot(diff1 < 0.5f));
        c1 += __popcll(m1 & __ballot(diff1 < 1.0f));
        c2 += __popcll(m1 & __ballot(diff1 < 2.0f));
        c3 += __popcll(m1 & __ballot(diff1 < 4.0f));
        cd += __popcll(m1);
    }
}

__global__ __launch_bounds__(TI) void lddt_partial(
    const float* __restrict__ pred,   // [B,N,3]
    const float* __restrict__ truec,  // [B,N,3]
    float2* __restrict__ part)        // [B, SLOTS]
{
    const int b = blockIdx.y;
    // decode linear tile index -> (a = i-tile, c = j-tile), c in [4a, 32)
    int r = blockIdx.x, a = 0;
    while (r >= 32 - 4 * a) { r -= 32 - 4 * a; ++a; }
    const int c = 4 * a + r;
    const int i0 = a * TI;
    const int j0 = c * TJ;
    const int t = threadIdx.x;
    const int wave = t >> 6;

    // pair-packed j-tile: group g holds j = 2g, 2g+1; 16-float (64 B) stride
    __shared__ float sj[NG * 16];

    if (t < TJ) {
        const float* pp = pred  + ((size_t)b * N + j0 + t) * 3;
        const float* tp = truec + ((size_t)b * N + j0 + t) * 3;
        float* dst = &sj[(t >> 1) * 16 + (t & 1)];
        dst[0]  = pp[0];  // px
        dst[2]  = pp[1];  // py
        dst[4]  = pp[2];  // pz
        dst[6]  = tp[0];  // tx
        dst[8]  = tp[1];  // ty
        dst[10] = tp[2];  // tz
    }

    const int i = i0 + t;
    const float* pi = pred  + ((size_t)b * N + i) * 3;
    const float* ti = truec + ((size_t)b * N + i) * 3;
    const float pix = pi[0], piy = pi[1], piz = pi[2];
    const float tix = ti[0], tiy = ti[1], tiz = ti[2];
    __syncthreads();

    unsigned c0 = 0, c1 = 0, c2 = 0, c3 = 0, cd = 0;

    if (c >= 4 * a + 4) {   // off-diagonal tile: all j > i guaranteed
        inner_loop<false>(sj, pix, piy, piz, tix, tiy, tiz, 0,
                          c0, c1, c2, c3, cd);
    } else {                // diagonal-band tile: SALU prefix-mask j>i
        const int k0 = j0 - (i0 + 64 * wave);
        inner_loop<true>(sj, pix, piy, piz, tix, tiy, tiz, k0,
                         c0, c1, c2, c3, cd);
    }

    // ballot counters are wave-uniform: lane 0 of each wave stores its slot
    if ((t & 63) == 0) {
        float n = 0.5f * (float)c0 + 0.25f * (float)c1
                + 0.125f * (float)c2 + 0.125f * (float)c3;
        part[(size_t)b * SLOTS + blockIdx.x * WPB + wave] =
            make_float2(n, (float)cd);
    }
}

// 512 threads = 8 waves; wave w reduces batch w's SLOTS slots.
__global__ __launch_bounds__(512) void lddt_reduce(
    const float2* __restrict__ part,  // [B, SLOTS]
    float* __restrict__ out)          // [1]
{
    const int t = threadIdx.x;
    const int w = t >> 6;     // batch
    const int l = t & 63;

    float n = 0.0f, d = 0.0f;
    for (int s = l; s < SLOTS; s += 64) {
        float2 v = part[(size_t)w * SLOTS + s];
        n += v.x;
        d += v.y;
    }
    for (int off = 32; off > 0; off >>= 1) {
        n += __shfl_down(n, off, 64);
        d += __shfl_down(d, off, 64);
    }

    __shared__ float acc[B];
    if (l == 0) acc[w] = 1.0f - n / fmaxf(d, 1e-8f);
    __syncthreads();

    if (t == 0) {
        float s = 0.0f;
        #pragma unroll
        for (int b = 0; b < B; ++b) s += acc[b];
        out[0] = s / (float)B;
    }
}

extern "C" void kernel_launch(void* const* d_in, const int* in_sizes, int n_in,
                              void* d_out, int out_size, void* d_ws, size_t ws_size,
                              hipStream_t stream)
{
    const float* pred  = (const float*)d_in[0];
    const float* truec = (const float*)d_in[1];
    float* out   = (float*)d_out;
    float2* part = (float2*)d_ws;   // B * SLOTS float2 = 36 KB

    dim3 grid(TILES, B);
    lddt_partial<<<grid, TI, 0, stream>>>(pred, truec, part);
    lddt_reduce<<<1, 512, 0, stream>>>(part, out);
}

// Round 7
// 72.483 us; speedup vs baseline: 1.0865x; 1.0865x over previous
//
#include <hip/hip_runtime.h>
#include <math.h>

// B=8, N=2048, coords [B,N,3] f32. LDDT loss, upper-triangle formulation:
// both distance matrices are symmetric so num/den over {j>i} equals the
// full-matrix ratio; j>i excludes the diagonal, making the reference's
// true_d > 1e-8 test vacuous for this data.
//
// R7 = R3 skeleton (256-thr blocks, 144 triangle tiles/batch, LDS j-tile,
// broadcast float4 reads) with the inner loop rebalanced across pipes.
// R3 was SALU-bound: the scalar unit is per-CU (shared by 4 SIMDs) and the
// ballot bookkeeping (4 s_and + 5 s_bcnt1 + 5 s_add = 14 SALU/iter/wave)
// exceeded the 42-cy VALU window (4x14=56 > 42). Changes:
//  - diff gating via cndmask (dg = keep ? |diff| : 1e9) removes the 4 s_and
//  - gram-trick distances with pre-scaled LDS tuples {-2x,-2y,-2z,|x|^2}:
//    d2 = fma,fma,fma,(add) = 4 VALU/distance (was 6); same formula as the
//    reference (incl. the max(d2,0) clamp)
//  - per-wave direct partial stores (ballot counters are wave-uniform)
constexpr int B  = 8;
constexpr int N  = 2048;
constexpr int TI = 256;        // i-points per block == threads (4 waves)
constexpr int TJ = 64;         // j-points per tile
constexpr int TILES = 144;     // per batch: c in [4a, 32), a in [0,8)
constexpr int WPB = TI / 64;   // waves per block
constexpr int SLOTS = TILES * WPB;   // 576 per batch

template <bool CHECK>
__device__ __forceinline__ void inner_loop(
    const float4* __restrict__ sjp,  // [TJ]: {-2px,-2py,-2pz,|p|^2}
    const float4* __restrict__ sjt,  // [TJ]: {-2tx,-2ty,-2tz,|t|^2}
    float pix, float piy, float piz, float x2pi,
    float tix, float tiy, float tiz, float x2ti,
    int k0, int lane,                // CHECK tiles: lane < k0+j <=> j0+j > i
    unsigned& c0, unsigned& c1, unsigned& c2, unsigned& c3, unsigned& cd)
{
    #pragma unroll 8
    for (int j = 0; j < TJ; ++j) {
        float4 P = sjp[j];
        float4 T = sjt[j];
        // d2 = |xi|^2 + |xj|^2 - 2 xi.xj  (gram trick, matches reference)
        float pd2 = fmaf(P.x, pix, fmaf(P.y, piy, fmaf(P.z, piz, x2pi + P.w)));
        float td2 = fmaf(T.x, tix, fmaf(T.y, tiy, fmaf(T.z, tiz, x2ti + T.w)));
        pd2 = fmaxf(pd2, 0.0f);
        td2 = fmaxf(td2, 0.0f);

        bool keep = td2 < 225.0f;            // local mask (squared domain)
        if (CHECK) keep = keep && (lane < k0 + j);

        float diff = __builtin_amdgcn_sqrtf(pd2) - __builtin_amdgcn_sqrtf(td2);
        // gate once on VALU so the 4 bin ballots need no SALU mask-AND
        float dg = keep ? fabsf(diff) : 1e9f;

        cd += __popcll(__ballot(keep));
        // cumulative bins: score = .5*[d<.5]+.25*[d<1]+.125*[d<2]+.125*[d<4]
        c0 += __popcll(__ballot(dg < 0.5f));
        c1 += __popcll(__ballot(dg < 1.0f));
        c2 += __popcll(__ballot(dg < 2.0f));
        c3 += __popcll(__ballot(dg < 4.0f));
    }
}

__global__ __launch_bounds__(TI) void lddt_partial(
    const float* __restrict__ pred,   // [B,N,3]
    const float* __restrict__ truec,  // [B,N,3]
    float2* __restrict__ part)        // [B, SLOTS]
{
    const int b = blockIdx.y;
    // decode linear tile index -> (a = i-tile, c = j-tile), c in [4a, 32)
    int r = blockIdx.x, a = 0;
    while (r >= 32 - 4 * a) { r -= 32 - 4 * a; ++a; }
    const int c = 4 * a + r;
    const int i0 = a * TI;
    const int j0 = c * TJ;
    const int t = threadIdx.x;
    const int wave = t >> 6;
    const int lane = t & 63;

    __shared__ float4 sjp[TJ];
    __shared__ float4 sjt[TJ];

    if (t < TJ) {
        const float* pp = pred  + ((size_t)b * N + j0 + t) * 3;
        const float* tp = truec + ((size_t)b * N + j0 + t) * 3;
        float px = pp[0], py = pp[1], pz = pp[2];
        float tx = tp[0], ty = tp[1], tz = tp[2];
        sjp[t] = make_float4(-2.0f * px, -2.0f * py, -2.0f * pz,
                             fmaf(px, px, fmaf(py, py, pz * pz)));
        sjt[t] = make_float4(-2.0f * tx, -2.0f * ty, -2.0f * tz,
                             fmaf(tx, tx, fmaf(ty, ty, tz * tz)));
    }

    const int i = i0 + t;
    const float* pi = pred  + ((size_t)b * N + i) * 3;
    const float* ti = truec + ((size_t)b * N + i) * 3;
    const float pix = pi[0], piy = pi[1], piz = pi[2];
    const float tix = ti[0], tiy = ti[1], tiz = ti[2];
    const float x2pi = fmaf(pix, pix, fmaf(piy, piy, piz * piz));
    const float x2ti = fmaf(tix, tix, fmaf(tiy, tiy, tiz * tiz));
    __syncthreads();

    unsigned c0 = 0, c1 = 0, c2 = 0, c3 = 0, cd = 0;

    if (c >= 4 * a + 4) {   // off-diagonal tile: all j > i guaranteed
        inner_loop<false>(sjp, sjt, pix, piy, piz, x2pi, tix, tiy, tiz, x2ti,
                          0, lane, c0, c1, c2, c3, cd);
    } else {                // diagonal-band tile: per-lane j>i compare
        const int k0 = j0 - (i0 + 64 * wave);
        inner_loop<true>(sjp, sjt, pix, piy, piz, x2pi, tix, tiy, tiz, x2ti,
                         k0, lane, c0, c1, c2, c3, cd);
    }

    // ballot counters are wave-uniform: lane 0 of each wave stores its slot
    if (lane == 0) {
        float n = 0.5f * (float)c0 + 0.25f * (float)c1
                + 0.125f * (float)c2 + 0.125f * (float)c3;
        part[(size_t)b * SLOTS + blockIdx.x * WPB + wave] =
            make_float2(n, (float)cd);
    }
}

// 512 threads = 8 waves; wave w reduces batch w's SLOTS slots.
__global__ __launch_bounds__(512) void lddt_reduce(
    const float2* __restrict__ part,  // [B, SLOTS]
    float* __restrict__ out)          // [1]
{
    const int t = threadIdx.x;
    const int w = t >> 6;     // batch
    const int l = t & 63;

    float n = 0.0f, d = 0.0f;
    for (int s = l; s < SLOTS; s += 64) {
        float2 v = part[(size_t)w * SLOTS + s];
        n += v.x;
        d += v.y;
    }
    for (int off = 32; off > 0; off >>= 1) {
        n += __shfl_down(n, off, 64);
        d += __shfl_down(d, off, 64);
    }

    __shared__ float acc[B];
    if (l == 0) acc[w] = 1.0f - n / fmaxf(d, 1e-8f);
    __syncthreads();

    if (t == 0) {
        float s = 0.0f;
        #pragma unroll
        for (int b = 0; b < B; ++b) s += acc[b];
        out[0] = s / (float)B;
    }
}

extern "C" void kernel_launch(void* const* d_in, const int* in_sizes, int n_in,
                              void* d_out, int out_size, void* d_ws, size_t ws_size,
                              hipStream_t stream)
{
    const float* pred  = (const float*)d_in[0];
    const float* truec = (const float*)d_in[1];
    float* out   = (float*)d_out;
    float2* part = (float2*)d_ws;   // B * SLOTS float2 = 36 KB

    dim3 grid(TILES, B);
    lddt_partial<<<grid, TI, 0, stream>>>(pred, truec, part);
    lddt_reduce<<<1, 512, 0, stream>>>(part, out);
}